// Round 4
// baseline (473.756 us; speedup 1.0000x reference)
//
#include <hip/hip_runtime.h>

constexpr int NROWS  = 131072;
constexpr int LDIM   = 300;
constexpr int KDIM   = 600;
constexpr int NPAD   = 304;              // 19 x 16 col-tiles (covers 300)
constexpr int KGRP   = 76;               // 608 / 8
constexpr int NCT    = 19;               // col-tiles per wave (all cols)
constexpr int MTILE  = 64;
constexpr int NBLKS  = NROWS / MTILE;    // 2048
constexpr int KSTEPS = 19;               // 608 / 32
constexpr int WT_ELEMS = KGRP * NPAD * 8;        // 184832 bf16 = 369664 B
constexpr size_t PART_OFF = 393216;              // byte offset of partials in ws

typedef __bf16 bf16x8 __attribute__((ext_vector_type(8)));
typedef float  f32x4  __attribute__((ext_vector_type(4)));

__device__ __forceinline__ unsigned short f2bf(float f) {
    unsigned u = __float_as_uint(f);
    u += 0x7fffu + ((u >> 16) & 1u);      // RNE; inputs are finite
    return (unsigned short)(u >> 16);
}

// relu + cvt 8 fp32 -> bf16x8 fragment (j = consecutive k)
__device__ __forceinline__ bf16x8 cvt8(const float4& a, const float4& b) {
    union { uint4 u; bf16x8 v; } r;
    r.u.x = (unsigned)f2bf(fmaxf(a.x, 0.f)) | ((unsigned)f2bf(fmaxf(a.y, 0.f)) << 16);
    r.u.y = (unsigned)f2bf(fmaxf(a.z, 0.f)) | ((unsigned)f2bf(fmaxf(a.w, 0.f)) << 16);
    r.u.z = (unsigned)f2bf(fmaxf(b.x, 0.f)) | ((unsigned)f2bf(fmaxf(b.y, 0.f)) << 16);
    r.u.w = (unsigned)f2bf(fmaxf(b.z, 0.f)) | ((unsigned)f2bf(fmaxf(b.w, 0.f)) << 16);
    return r.v;
}

// ---------------- kernel 1: W1 -> bf16, fragment-ready layout [kg][n][j] ----
__global__ void prep_w1(const float* __restrict__ w1, unsigned short* __restrict__ wt) {
    int idx = blockIdx.x * 256 + threadIdx.x;
    if (idx >= WT_ELEMS) return;
    int j    = idx & 7;
    int rest = idx >> 3;
    int n    = rest % NPAD;
    int kg   = rest / NPAD;
    int k    = kg * 8 + j;
    float v = 0.f;
    if (k < KDIM && n < LDIM) v = w1[k * LDIM + n];
    wt[idx] = f2bf(v);
}

// ---------------- kernel 2: fused GEMM + epilogue ---------------------------
// NO LDS staging, NO barriers in the K-loop. Each wave owns 32 rows x 304 cols:
// A fragments are built directly from global (two float4 per lane per row-tile
// per K-step: lane l = row l&15, k-chunk (l>>4)*8 — 16 contiguous 128 B
// segments per wave, well coalesced), relu+bf16-cvt in-register. B streams
// from the L2-resident wt. Waves are fully independent until the tiny loss
// fold at the end — the barrier/LDS latency chain of rounds 0-3 is gone.
__launch_bounds__(128, 2)
__global__ void main_kernel(const float* __restrict__ sbj, const float* __restrict__ obj,
                            const float* __restrict__ rlts,
                            const float* __restrict__ spa_w, const float* __restrict__ spa_b,
                            const float* __restrict__ b1, const float* __restrict__ w2,
                            const float* __restrict__ b2,
                            const unsigned short* __restrict__ wt,
                            float* __restrict__ out_scores, float* __restrict__ part) {
    __shared__ float redbuf[2][8];

    const int tid  = threadIdx.x;
    const int lane = tid & 63;
    const int wv   = tid >> 6;     // 0..1 — each wave owns 32 rows
    const int l4   = lane & 15;    // MFMA row/col index
    const int q4   = lane >> 4;    // MFMA k-group (0..3)

    const int  blk   = blockIdx.x;
    const long wrow0 = (long)blk * MTILE + (long)wv * 32;

    // Per-lane A row bases for the two 16-row tiles (rt = 0,1)
    const float* sb[2];
    const float* ob[2];
    #pragma unroll
    for (int rt = 0; rt < 2; ++rt) {
        const long r = wrow0 + rt * 16 + l4;
        sb[rt] = sbj + r * (long)LDIM + q4 * 8;
        ob[rt] = obj + r * (long)LDIM + q4 * 8 - LDIM;   // valid only when deref'd at k>=300
    }
    const unsigned short* bb = wt + ((size_t)q4 * NPAD + l4) * 8;

    f32x4 acc[2][NCT];
    #pragma unroll
    for (int rt = 0; rt < 2; ++rt)
        #pragma unroll
        for (int ct = 0; ct < NCT; ++ct)
            acc[rt][ct] = (f32x4)(0.f);

    float4 ar[2][2][2];            // [slot][rt][lo/hi] — static-indexed under full unroll

    auto ldA = [&](int kt, int slot) {
        #pragma unroll
        for (int rt = 0; rt < 2; ++rt) {
            const int kf = kt * 32 + q4 * 8;
            float4 va, vb;
            if (kf < LDIM)          va = *(const float4*)(sb[rt] + kt * 32);
            else if (kf < KDIM)     va = *(const float4*)(ob[rt] + kt * 32);
            else                    va = make_float4(0.f, 0.f, 0.f, 0.f);
            if (kf + 4 < LDIM)      vb = *(const float4*)(sb[rt] + kt * 32 + 4);
            else if (kf + 4 < KDIM) vb = *(const float4*)(ob[rt] + kt * 32 + 4);
            else                    vb = make_float4(0.f, 0.f, 0.f, 0.f);
            ar[slot][rt][0] = va;
            ar[slot][rt][1] = vb;
        }
    };

    ldA(0, 0);

    #pragma unroll
    for (int kt = 0; kt < KSTEPS; ++kt) {
        const int slot = kt & 1;
        if (kt + 1 < KSTEPS) ldA(kt + 1, slot ^ 1);   // depth-1 reg prefetch, no barrier

        bf16x8 af[2];
        af[0] = cvt8(ar[slot][0][0], ar[slot][0][1]);
        af[1] = cvt8(ar[slot][1][0], ar[slot][1][1]);

        const unsigned short* bk = bb + (size_t)kt * 4 * NPAD * 8;

        // B in two half-chunks to bound live registers (acc already holds 152)
        bf16x8 bfr[10];
        #pragma unroll
        for (int c = 0; c < 10; ++c) bfr[c] = *(const bf16x8*)(bk + c * 128);
        #pragma unroll
        for (int c = 0; c < 10; ++c) {
            acc[0][c] = __builtin_amdgcn_mfma_f32_16x16x32_bf16(af[0], bfr[c], acc[0][c], 0, 0, 0);
            acc[1][c] = __builtin_amdgcn_mfma_f32_16x16x32_bf16(af[1], bfr[c], acc[1][c], 0, 0, 0);
        }
        #pragma unroll
        for (int c = 0; c < 9; ++c) bfr[c] = *(const bf16x8*)(bk + (10 + c) * 128);
        #pragma unroll
        for (int c = 0; c < 9; ++c) {
            acc[0][10 + c] = __builtin_amdgcn_mfma_f32_16x16x32_bf16(af[0], bfr[c], acc[0][10 + c], 0, 0, 0);
            acc[1][10 + c] = __builtin_amdgcn_mfma_f32_16x16x32_bf16(af[1], bfr[c], acc[1][10 + c], 0, 0, 0);
        }
    }

    // ---- epilogue: bias + relu + dot with w2 (all in-wave, shuffle-only) ----
    // C/D layout (m89): col = lane&15, row_local = rt*16 + (lane>>4)*4 + reg
    float pr[2][4];
    #pragma unroll
    for (int rt = 0; rt < 2; ++rt)
        #pragma unroll
        for (int r = 0; r < 4; ++r) pr[rt][r] = 0.f;

    #pragma unroll
    for (int ct = 0; ct < NCT; ++ct) {
        const int n = ct * 16 + l4;
        if (n < LDIM) {
            const float b1n = b1[n];
            const float w2n = w2[n];
            #pragma unroll
            for (int rt = 0; rt < 2; ++rt)
                #pragma unroll
                for (int r = 0; r < 4; ++r) {
                    float h = fmaxf(acc[rt][ct][r] + b1n, 0.f);
                    pr[rt][r] = fmaf(h, w2n, pr[rt][r]);
                }
        }
    }
    // butterfly over the 16 col-lanes: every lane ends with the full row sum
    #pragma unroll
    for (int off = 1; off < 16; off <<= 1)
        #pragma unroll
        for (int rt = 0; rt < 2; ++rt)
            #pragma unroll
            for (int r = 0; r < 4; ++r)
                pr[rt][r] += __shfl_xor(pr[rt][r], off, 64);

    // redistribute: lane t (<32) picks row t = rt*16 + q4src*4 + r
    const int t   = lane;
    const int src = ((t >> 2) & 3) << 4;
    const float a00 = __shfl(pr[0][0], src, 64), a01 = __shfl(pr[0][1], src, 64);
    const float a02 = __shfl(pr[0][2], src, 64), a03 = __shfl(pr[0][3], src, 64);
    const float a10 = __shfl(pr[1][0], src, 64), a11 = __shfl(pr[1][1], src, 64);
    const float a12 = __shfl(pr[1][2], src, 64), a13 = __shfl(pr[1][3], src, 64);
    const int rs = t & 3;
    const float v0 = (rs == 0) ? a00 : (rs == 1) ? a01 : (rs == 2) ? a02 : a03;
    const float v1 = (rs == 0) ? a10 : (rs == 1) ? a11 : (rs == 2) ? a12 : a13;
    const float lanraw = ((t >> 4) & 1) ? v1 : v0;

    // ---- per-row: box features, sigmoid, loss terms (lanes 0..31) ----
    float s_loss = 0.f, s_cp = 0.f, s_cn = 0.f, s_pr = 0.f, s_nr = 0.f;
    if (t < 32) {
        const long g   = wrow0 + t;
        const float lan = lanraw + b2[0];
        const float* rr = rlts + g * 15;
        const float label = rr[4];
        const float sx1 = rr[5],  sy1 = rr[6],  sx2 = rr[7],  sy2 = rr[8];
        const float ox1 = rr[10], oy1 = rr[11], ox2 = rr[12], oy2 = rr[13];
        const float sw = sx2 - sx1, sh = sy2 - sy1, ow = ox2 - ox1, oh = oy2 - oy1;
        float bs = spa_w[0] * ((sx1 - ox1) / sw)
                 + spa_w[1] * ((sy1 - oy1) / sh)
                 + spa_w[2] * logf(sw / ow)
                 + spa_w[3] * logf(sh / oh)
                 + spa_w[4] * ((ox1 - sx1) / ow)
                 + spa_w[5] * ((oy1 - sy1) / oh)
                 + spa_w[6] * logf(ow / sw)
                 + spa_w[7] * logf(oh / sh)
                 + spa_b[0];
        const float z = lan + bs;
        const float s = 1.f / (1.f + expf(-z));
        out_scores[g] = s;
        const float ls = fmaxf(logf(fminf(fmaxf(s, 1e-12f), 1.f)), -100.f);
        const float l1 = fmaxf(logf(fminf(fmaxf(1.f - s, 1e-12f), 1.f)), -100.f);
        const bool ys = label > 0.f;
        s_loss = ys ? ls : l1;
        s_cp   = ys ? 1.f : 0.f;
        s_cn   = ys ? 0.f : 1.f;
        s_pr   = (!ys && s >= 0.5f) ? 1.f : 0.f;  // "N_pos_right" per reference
        s_nr   = (ys && s < 0.5f)  ? 1.f : 0.f;   // "N_neg_right" per reference
    }
    #pragma unroll
    for (int off = 1; off < 64; off <<= 1) {
        s_loss += __shfl_xor(s_loss, off, 64);
        s_cp   += __shfl_xor(s_cp, off, 64);
        s_cn   += __shfl_xor(s_cn, off, 64);
        s_pr   += __shfl_xor(s_pr, off, 64);
        s_nr   += __shfl_xor(s_nr, off, 64);
    }
    if (lane == 0) {
        redbuf[wv][0] = s_loss; redbuf[wv][1] = s_cp; redbuf[wv][2] = s_cn;
        redbuf[wv][3] = s_pr;   redbuf[wv][4] = s_nr;
    }
    __syncthreads();               // the only block-wide barrier in the kernel
    if (tid == 0) {
        float t0 = 0.f, t1 = 0.f, t2 = 0.f, t3 = 0.f, t4 = 0.f;
        for (int w = 0; w < 2; ++w) {
            t0 += redbuf[w][0]; t1 += redbuf[w][1]; t2 += redbuf[w][2];
            t3 += redbuf[w][3]; t4 += redbuf[w][4];
        }
        part[blk * 8 + 0] = t0; part[blk * 8 + 1] = t1; part[blk * 8 + 2] = t2;
        part[blk * 8 + 3] = t3; part[blk * 8 + 4] = t4;
    }
}

// ---------------- kernel 3: fold 2048 block partials ------------------------
__global__ void final_reduce(const float* __restrict__ part, float* __restrict__ out) {
    __shared__ float red[4][8];
    const int tid = threadIdx.x;
    const int lane = tid & 63, wv = tid >> 6;
    float a0 = 0.f, a1 = 0.f, a2 = 0.f, a3 = 0.f, a4 = 0.f;
    for (int b = tid; b < NBLKS; b += 256) {
        a0 += part[b * 8 + 0]; a1 += part[b * 8 + 1]; a2 += part[b * 8 + 2];
        a3 += part[b * 8 + 3]; a4 += part[b * 8 + 4];
    }
    #pragma unroll
    for (int off = 1; off < 64; off <<= 1) {
        a0 += __shfl_xor(a0, off, 64); a1 += __shfl_xor(a1, off, 64);
        a2 += __shfl_xor(a2, off, 64); a3 += __shfl_xor(a3, off, 64);
        a4 += __shfl_xor(a4, off, 64);
    }
    if (lane == 0) { red[wv][0] = a0; red[wv][1] = a1; red[wv][2] = a2; red[wv][3] = a3; red[wv][4] = a4; }
    __syncthreads();
    if (tid == 0) {
        float t0 = 0.f, t1 = 0.f, t2 = 0.f, t3 = 0.f, t4 = 0.f;
        for (int w = 0; w < 4; ++w) {
            t0 += red[w][0]; t1 += red[w][1]; t2 += red[w][2]; t3 += red[w][3]; t4 += red[w][4];
        }
        out[NROWS + 0] = -t0 / (float)NROWS;       // loss
        out[NROWS + 1] = t3 / t1;                  // recall_pos
        out[NROWS + 2] = t4 / t2;                  // recall_neg
        out[NROWS + 3] = (t3 + t4) / (t1 + t2);    // recall_all
    }
}

extern "C" void kernel_launch(void* const* d_in, const int* in_sizes, int n_in,
                              void* d_out, int out_size, void* d_ws, size_t ws_size,
                              hipStream_t stream) {
    const float* sbj   = (const float*)d_in[0];
    const float* obj   = (const float*)d_in[1];
    const float* rlts  = (const float*)d_in[2];
    const float* spa_w = (const float*)d_in[3];
    const float* spa_b = (const float*)d_in[4];
    const float* w1    = (const float*)d_in[5];
    const float* b1    = (const float*)d_in[6];
    const float* w2    = (const float*)d_in[7];
    const float* b2    = (const float*)d_in[8];
    float* out = (float*)d_out;

    unsigned short* wt = (unsigned short*)d_ws;
    float* part = (float*)((char*)d_ws + PART_OFF);

    prep_w1<<<(WT_ELEMS + 255) / 256, 256, 0, stream>>>(w1, wt);
    main_kernel<<<NBLKS, 128, 0, stream>>>(sbj, obj, rlts, spa_w, spa_b, b1, w2, b2, wt, out, part);
    final_reduce<<<1, 256, 0, stream>>>(part, out);
}

// Round 5
// 372.835 us; speedup vs baseline: 1.2707x; 1.2707x over previous
//
#include <hip/hip_runtime.h>

constexpr int NROWS  = 131072;
constexpr int LDIM   = 300;
constexpr int KDIM   = 600;
constexpr int NPAD   = 320;
constexpr int KGRP   = 76;               // 608 / 8
constexpr int MTILE  = 64;
constexpr int NBLKS  = NROWS / MTILE;    // 2048
constexpr int KSTEPS = 19;               // 608 / 32
constexpr int CHUNK  = 4;                // K-steps per LDS buffer / per barrier
constexpr int WT_ELEMS = KGRP * NPAD * 8;        // 194560 bf16
constexpr size_t PART_OFF = 393216;              // byte offset of partials in ws
constexpr int ASTRIDE = 40;              // shorts per row (80 B) — 2-way max on reads
constexpr int STEPSH  = MTILE * ASTRIDE; // shorts per step buffer (2560)

typedef __bf16 bf16x8 __attribute__((ext_vector_type(8)));
typedef float  f32x4  __attribute__((ext_vector_type(4)));

__device__ __forceinline__ unsigned short f2bf(float f) {
    unsigned u = __float_as_uint(f);
    u += 0x7fffu + ((u >> 16) & 1u);      // RNE; inputs are finite
    return (unsigned short)(u >> 16);
}

// ---------------- kernel 1: W1 -> bf16, fragment-ready layout [kg][n][j] ----
__global__ void prep_w1(const float* __restrict__ w1, unsigned short* __restrict__ wt) {
    int idx = blockIdx.x * 256 + threadIdx.x;
    if (idx >= WT_ELEMS) return;
    int j    = idx & 7;
    int rest = idx >> 3;
    int n    = rest % NPAD;
    int kg   = rest / NPAD;
    int k    = kg * 8 + j;
    float v = 0.f;
    if (k < KDIM && n < LDIM) v = w1[k * LDIM + n];
    wt[idx] = f2bf(v);
}

// ---------------- kernel 2: fused GEMM + epilogue ---------------------------
// K-loop chunked 4 steps per barrier (5 barriers instead of 19). Per chunk:
// burst-issue the next chunk's 8 float4 HBM loads up front (~500 cy of MFMA
// covers the latency), compute 4 steps from LDS with per-step B rotation that
// crosses chunk boundaries, cvt+ds_write at chunk end, then lgkmcnt(0) + RAW
// s_barrier (no vmem drain — r3's proven idiom). This quadruples the sync
// period, raising the load-queue duty cycle that capped rounds 0-3 at ~1.1 TB/s.
__launch_bounds__(256, 2)
__global__ void main_kernel(const float* __restrict__ sbj, const float* __restrict__ obj,
                            const float* __restrict__ rlts,
                            const float* __restrict__ spa_w, const float* __restrict__ spa_b,
                            const float* __restrict__ b1, const float* __restrict__ w2,
                            const float* __restrict__ b2,
                            const unsigned short* __restrict__ wt,
                            float* __restrict__ out_scores, float* __restrict__ part) {
    __shared__ __attribute__((aligned(16))) short A_lds[2][CHUNK * STEPSH]; // 40960 B
    __shared__ float lanpart[4][MTILE];
    __shared__ float redbuf[4][8];

    const int tid  = threadIdx.x;
    const int lane = tid & 63;
    const int wv   = tid >> 6;     // 0..3 — each wave owns 80 cols
    const int l4   = lane & 15;    // MFMA row/col index
    const int q4   = lane >> 4;    // MFMA k-group (0..3)
    const int nbase = wv * 80;

    const int  blk  = blockIdx.x;
    const long row0 = (long)blk * MTILE;

    // A staging map: thread t loads rows (t>>3) and (t>>3)+32, k-quad t&7
    const int a_quad = tid & 7;
    const int a_row  = tid >> 3;   // 0..31

    f32x4 acc[4][5];
    #pragma unroll
    for (int rt = 0; rt < 4; ++rt)
        #pragma unroll
        for (int ct = 0; ct < 5; ++ct)
            acc[rt][ct] = (f32x4)(0.f);

    float4 pre[CHUNK][2];          // one chunk of A in registers (static-indexed)
    bf16x8 bfr[2][5];              // per-step B rotation (crosses chunk bounds)

    const unsigned short* wbase = wt + ((size_t)q4 * NPAD + nbase + l4) * 8;

    auto ldA = [&](int kt, int slot) {
        const int k0 = kt * 32 + a_quad * 4;   // mult of 4; 300 % 4 == 0 → no straddle
        #pragma unroll
        for (int i = 0; i < 2; ++i) {
            const long grow = row0 + a_row + i * 32;
            if (k0 < LDIM)       pre[slot][i] = *(const float4*)(sbj + grow * LDIM + k0);
            else if (k0 < KDIM)  pre[slot][i] = *(const float4*)(obj + grow * LDIM + (k0 - LDIM));
            else                 pre[slot][i] = make_float4(0.f, 0.f, 0.f, 0.f);
        }
    };
    auto stA = [&](int slot, int buf, int s) {
        #pragma unroll
        for (int i = 0; i < 2; ++i) {
            const int row = a_row + i * 32;
            unsigned h0 = f2bf(fmaxf(pre[slot][i].x, 0.f));
            unsigned h1 = f2bf(fmaxf(pre[slot][i].y, 0.f));
            unsigned h2 = f2bf(fmaxf(pre[slot][i].z, 0.f));
            unsigned h3 = f2bf(fmaxf(pre[slot][i].w, 0.f));
            uint2 pk = make_uint2(h0 | (h1 << 16), h2 | (h3 << 16));
            *(uint2*)&A_lds[buf][s * STEPSH + row * ASTRIDE + a_quad * 4] = pk;
        }
    };
    auto ldB = [&](int u, int rb) {
        #pragma unroll
        for (int ct = 0; ct < 5; ++ct)
            bfr[rb][ct] = *(const bf16x8*)(wbase + (size_t)u * 4 * NPAD * 8 + ct * 16 * 8);
    };

    // Prologue: B(0) + chunk 0 burst, commit, one barrier.
    ldB(0, 0);
    #pragma unroll
    for (int s = 0; s < CHUNK; ++s) ldA(s, s);
    #pragma unroll
    for (int s = 0; s < CHUNK; ++s) stA(s, 0, s);
    asm volatile("s_waitcnt lgkmcnt(0)" ::: "memory");
    __builtin_amdgcn_s_barrier();

    #pragma unroll
    for (int c = 0; c < 5; ++c) {
        const int buf = c & 1;
        const int s0  = c * CHUNK;
        const int ns  = (c == 4) ? 3 : 4;   // steps in this chunk (19 = 4*4+3)
        const int nn  = (c == 3) ? 3 : 4;   // steps in next chunk

        // (1) burst-issue next chunk's A loads — in flight during this chunk's MFMAs
        if (c < 4) {
            #pragma unroll
            for (int s = 0; s < nn; ++s) ldA(s0 + CHUNK + s, s);
        }

        // (2) compute ns steps from LDS[buf]; B rotates one step ahead
        #pragma unroll
        for (int s = 0; s < ns; ++s) {
            const int u = s0 + s;
            bf16x8 af[4];
            #pragma unroll
            for (int rt = 0; rt < 4; ++rt)
                af[rt] = *(const bf16x8*)&A_lds[buf][s * STEPSH + (rt * 16 + l4) * ASTRIDE + q4 * 8];

            if (u + 1 < KSTEPS) ldB(u + 1, (u + 1) & 1);

            #pragma unroll
            for (int ct = 0; ct < 5; ++ct)
                #pragma unroll
                for (int rt = 0; rt < 4; ++rt)
                    acc[rt][ct] = __builtin_amdgcn_mfma_f32_16x16x32_bf16(af[rt], bfr[u & 1][ct], acc[rt][ct], 0, 0, 0);
        }

        // (3) commit next chunk (counted vmcnt: B loads issued later stay in
        //     flight), publish via lgkmcnt(0) + RAW barrier (no vmem drain).
        if (c < 4) {
            #pragma unroll
            for (int s = 0; s < nn; ++s) stA(s, buf ^ 1, s);
            asm volatile("s_waitcnt lgkmcnt(0)" ::: "memory");
            __builtin_amdgcn_s_barrier();
        }
    }

    // ---- epilogue: bias + relu + dot with w2 ----
    // C/D layout (m89): col = lane&15, row = (lane>>4)*4 + reg
    float part_r[4][4];
    #pragma unroll
    for (int rt = 0; rt < 4; ++rt)
        #pragma unroll
        for (int r = 0; r < 4; ++r) part_r[rt][r] = 0.f;

    #pragma unroll
    for (int ct = 0; ct < 5; ++ct) {
        const int n = nbase + ct * 16 + l4;
        if (n < LDIM) {
            const float b1n = b1[n];
            const float w2n = w2[n];
            #pragma unroll
            for (int rt = 0; rt < 4; ++rt)
                #pragma unroll
                for (int r = 0; r < 4; ++r) {
                    float h = fmaxf(acc[rt][ct][r] + b1n, 0.f);
                    part_r[rt][r] = fmaf(h, w2n, part_r[rt][r]);
                }
        }
    }
    // reduce over the 16 col-lanes (xor of lane bits 0..3)
    #pragma unroll
    for (int off = 1; off < 16; off <<= 1)
        #pragma unroll
        for (int rt = 0; rt < 4; ++rt)
            #pragma unroll
            for (int r = 0; r < 4; ++r)
                part_r[rt][r] += __shfl_xor(part_r[rt][r], off, 64);

    if (l4 == 0) {
        #pragma unroll
        for (int rt = 0; rt < 4; ++rt)
            #pragma unroll
            for (int r = 0; r < 4; ++r)
                lanpart[wv][rt * 16 + q4 * 4 + r] = part_r[rt][r];
    }
    __syncthreads();

    // ---- per-row: box features, sigmoid, loss terms ----
    float s_loss = 0.f, s_cp = 0.f, s_cn = 0.f, s_pr = 0.f, s_nr = 0.f;
    if (tid < MTILE) {
        const long g   = row0 + tid;
        const float lan = lanpart[0][tid] + lanpart[1][tid] + lanpart[2][tid] + lanpart[3][tid] + b2[0];
        const float* rr = rlts + g * 15;
        const float label = rr[4];
        const float sx1 = rr[5],  sy1 = rr[6],  sx2 = rr[7],  sy2 = rr[8];
        const float ox1 = rr[10], oy1 = rr[11], ox2 = rr[12], oy2 = rr[13];
        const float sw = sx2 - sx1, sh = sy2 - sy1, ow = ox2 - ox1, oh = oy2 - oy1;
        float bs = spa_w[0] * ((sx1 - ox1) / sw)
                 + spa_w[1] * ((sy1 - oy1) / sh)
                 + spa_w[2] * logf(sw / ow)
                 + spa_w[3] * logf(sh / oh)
                 + spa_w[4] * ((ox1 - sx1) / ow)
                 + spa_w[5] * ((oy1 - sy1) / oh)
                 + spa_w[6] * logf(ow / sw)
                 + spa_w[7] * logf(oh / sh)
                 + spa_b[0];
        const float z = lan + bs;
        const float s = 1.f / (1.f + expf(-z));
        out_scores[g] = s;
        const float ls = fmaxf(logf(fminf(fmaxf(s, 1e-12f), 1.f)), -100.f);
        const float l1 = fmaxf(logf(fminf(fmaxf(1.f - s, 1e-12f), 1.f)), -100.f);
        const bool ys = label > 0.f;
        s_loss = ys ? ls : l1;
        s_cp   = ys ? 1.f : 0.f;
        s_cn   = ys ? 0.f : 1.f;
        s_pr   = (!ys && s >= 0.5f) ? 1.f : 0.f;  // "N_pos_right" per reference
        s_nr   = (ys && s < 0.5f)  ? 1.f : 0.f;   // "N_neg_right" per reference
    }
    #pragma unroll
    for (int off = 1; off < 64; off <<= 1) {
        s_loss += __shfl_xor(s_loss, off, 64);
        s_cp   += __shfl_xor(s_cp, off, 64);
        s_cn   += __shfl_xor(s_cn, off, 64);
        s_pr   += __shfl_xor(s_pr, off, 64);
        s_nr   += __shfl_xor(s_nr, off, 64);
    }
    if (lane == 0) {
        redbuf[wv][0] = s_loss; redbuf[wv][1] = s_cp; redbuf[wv][2] = s_cn;
        redbuf[wv][3] = s_pr;   redbuf[wv][4] = s_nr;
    }
    __syncthreads();
    if (tid == 0) {
        float t0 = 0.f, t1 = 0.f, t2 = 0.f, t3 = 0.f, t4 = 0.f;
        for (int w = 0; w < 4; ++w) {
            t0 += redbuf[w][0]; t1 += redbuf[w][1]; t2 += redbuf[w][2];
            t3 += redbuf[w][3]; t4 += redbuf[w][4];
        }
        part[blk * 8 + 0] = t0; part[blk * 8 + 1] = t1; part[blk * 8 + 2] = t2;
        part[blk * 8 + 3] = t3; part[blk * 8 + 4] = t4;
    }
}

// ---------------- kernel 3: fold 2048 block partials ------------------------
__global__ void final_reduce(const float* __restrict__ part, float* __restrict__ out) {
    __shared__ float red[4][8];
    const int tid = threadIdx.x;
    const int lane = tid & 63, wv = tid >> 6;
    float a0 = 0.f, a1 = 0.f, a2 = 0.f, a3 = 0.f, a4 = 0.f;
    for (int b = tid; b < NBLKS; b += 256) {
        a0 += part[b * 8 + 0]; a1 += part[b * 8 + 1]; a2 += part[b * 8 + 2];
        a3 += part[b * 8 + 3]; a4 += part[b * 8 + 4];
    }
    #pragma unroll
    for (int off = 1; off < 64; off <<= 1) {
        a0 += __shfl_xor(a0, off, 64); a1 += __shfl_xor(a1, off, 64);
        a2 += __shfl_xor(a2, off, 64); a3 += __shfl_xor(a3, off, 64);
        a4 += __shfl_xor(a4, off, 64);
    }
    if (lane == 0) { red[wv][0] = a0; red[wv][1] = a1; red[wv][2] = a2; red[wv][3] = a3; red[wv][4] = a4; }
    __syncthreads();
    if (tid == 0) {
        float t0 = 0.f, t1 = 0.f, t2 = 0.f, t3 = 0.f, t4 = 0.f;
        for (int w = 0; w < 4; ++w) {
            t0 += red[w][0]; t1 += red[w][1]; t2 += red[w][2]; t3 += red[w][3]; t4 += red[w][4];
        }
        out[NROWS + 0] = -t0 / (float)NROWS;       // loss
        out[NROWS + 1] = t3 / t1;                  // recall_pos
        out[NROWS + 2] = t4 / t2;                  // recall_neg
        out[NROWS + 3] = (t3 + t4) / (t1 + t2);    // recall_all
    }
}

extern "C" void kernel_launch(void* const* d_in, const int* in_sizes, int n_in,
                              void* d_out, int out_size, void* d_ws, size_t ws_size,
                              hipStream_t stream) {
    const float* sbj   = (const float*)d_in[0];
    const float* obj   = (const float*)d_in[1];
    const float* rlts  = (const float*)d_in[2];
    const float* spa_w = (const float*)d_in[3];
    const float* spa_b = (const float*)d_in[4];
    const float* w1    = (const float*)d_in[5];
    const float* b1    = (const float*)d_in[6];
    const float* w2    = (const float*)d_in[7];
    const float* b2    = (const float*)d_in[8];
    float* out = (float*)d_out;

    unsigned short* wt = (unsigned short*)d_ws;
    float* part = (float*)((char*)d_ws + PART_OFF);

    prep_w1<<<(WT_ELEMS + 255) / 256, 256, 0, stream>>>(w1, wt);
    main_kernel<<<NBLKS, 256, 0, stream>>>(sbj, obj, rlts, spa_w, spa_b, b1, w2, b2, wt, out, part);
    final_reduce<<<1, 256, 0, stream>>>(part, out);
}